// Round 2
// baseline (41823.886 us; speedup 1.0000x reference)
//
#include <hip/hip_runtime.h>
#include <cstdint>
#include <cstddef>

#define MINN 1e-15f
#define EPSA 1e-7f

// ---------- device helpers ----------
__device__ __forceinline__ float tan_k_(float u, float sk) {
    float a = fminf(fmaxf(sk * u, -15.f), 15.f);
    return tanhf(a) / sk;
}
__device__ __forceinline__ float artan_k_(float u, float sk) {
    float a = fminf(fmaxf(sk * u, -1.f + EPSA), 1.f - EPSA);
    return atanhf(a) / sk;
}
// mobius_add elementwise part with precomputed scalars x2,y2,xy
__device__ __forceinline__ float madd_c(float x, float y, float x2, float y2, float xy, float k) {
    float num = (1.f - 2.f * k * xy - k * y2) * x + (1.f + k * x2) * y;
    float den = 1.f - 2.f * k * xy + k * k * x2 * y2;
    return num / fmaxf(den, MINN);
}
__device__ __forceinline__ float wave_sum(float v) {
#pragma unroll
    for (int off = 32; off; off >>= 1) v += __shfl_xor(v, off, 64);
    return v;
}
// block(256)-wide reduce of 4 values; returns broadcast sums. 2 barriers.
__device__ __forceinline__ float4 block_reduce4(float4 v, float* sred) {
#pragma unroll
    for (int off = 32; off; off >>= 1) {
        v.x += __shfl_xor(v.x, off, 64);
        v.y += __shfl_xor(v.y, off, 64);
        v.z += __shfl_xor(v.z, off, 64);
        v.w += __shfl_xor(v.w, off, 64);
    }
    int w = threadIdx.x >> 6;
    __syncthreads();  // protect sred from previous use
    if ((threadIdx.x & 63) == 0) {
        sred[w * 4 + 0] = v.x; sred[w * 4 + 1] = v.y;
        sred[w * 4 + 2] = v.z; sred[w * 4 + 3] = v.w;
    }
    __syncthreads();
    v.x = sred[0] + sred[4] + sred[8] + sred[12];
    v.y = sred[1] + sred[5] + sred[9] + sred[13];
    v.z = sred[2] + sred[6] + sred[10] + sred[14];
    v.w = sred[3] + sred[7] + sred[11] + sred[15];
    return v;
}

// ---------- K1: transpose 4 weight matrices [768x256] -> [256x768] ----------
__global__ __launch_bounds__(256) void kt_transpose(
    const float* __restrict__ a0, const float* __restrict__ a1,
    const float* __restrict__ a2, const float* __restrict__ a3,
    float* __restrict__ o0, float* __restrict__ o1,
    float* __restrict__ o2, float* __restrict__ o3) {
    int idx = blockIdx.x * 256 + threadIdx.x;  // 4*196608 total
    int m = idx / 196608, rem = idx % 196608;
    int j = rem >> 8, kk = rem & 255;  // j<768 rows, kk<256 cols of source
    const float* in = (m == 0) ? a0 : (m == 1) ? a1 : (m == 2) ? a2 : a3;
    float* outp     = (m == 0) ? o0 : (m == 1) ? o1 : (m == 2) ? o2 : o3;
    outp[kk * 768 + j] = in[j * 256 + kk];
}

// ---------- K2: copy h0 (both layers) into carry buffer ----------
__global__ __launch_bounds__(256) void kt_init(
    const float* __restrict__ h0, float* __restrict__ hcar) {
    int i = blockIdx.x * 256 + threadIdx.x;  // 32768
    hcar[i] = h0[i];
}
// ---------- K7: copy carries to d_out ht slots ----------
__global__ __launch_bounds__(256) void kt_final(
    const float* __restrict__ hcar, float* __restrict__ dst) {
    int i = blockIdx.x * 256 + threadIdx.x;  // 32768
    dst[i] = hcar[i];
}

// ---------- K3: per-row scale (expmap0 fused) + artan factor ----------
// Chunk of RC=4096 rows; row address = (r>>6)*strideB + (r&63)*256.
// mode 0: input needs expmap0 -> s = tan_k(n)/n ; mode 1: hyperbolic -> s=1
__global__ __launch_bounds__(256) void kt_rowscale(
    const float* __restrict__ src, long long strideB,
    float* __restrict__ s_arr, float* __restrict__ ax_arr,
    const float* __restrict__ kptr, int mode) {
    int lane = threadIdx.x & 63;
    int r = blockIdx.x * 4 + (threadIdx.x >> 6);  // r < 4096
    float k = kptr[0], sk = sqrtf(-k);
    size_t off = (size_t)(r >> 6) * strideB + (size_t)(r & 63) * 256 + lane * 4;
    float4 v = *(const float4*)&src[off];
    float n2 = wave_sum(v.x * v.x + v.y * v.y + v.z * v.z + v.w * v.w);
    float n = sqrtf(n2);
    float s, xn;
    if (mode == 0) {
        float nrm = fmaxf(n, MINN);
        float tk = tan_k_(nrm, sk);
        s = tk / nrm;
        xn = fmaxf(tk * (n / nrm), MINN);
    } else {
        s = 1.f;
        xn = fmaxf(n, MINN);
    }
    float ax = artan_k_(xn, sk) / xn;
    if (lane == 0) { s_arr[r] = s; ax_arr[r] = ax; }
}

// ---------- K4: C[4096x768] = diag(s)*A_chunk[4096x256] @ Bt[256x768] ----------
__global__ __launch_bounds__(256) void kt_gemm(
    const float* __restrict__ A, long long strideB,
    const float* __restrict__ s_arr,
    const float* __restrict__ Bt, float* __restrict__ C) {
    __shared__ float As[16][68];
    __shared__ float Bs[16][68];
    __shared__ float sS[64];
    int tid = threadIdx.x;
    int row0 = blockIdx.y * 64, col0 = blockIdx.x * 64;
    if (tid < 64) sS[tid] = s_arr[row0 + tid];
    int ty = tid >> 4, tx = tid & 15;
    int ra = tid >> 2, kq = tid & 3;
    int kb = tid >> 4, cq = tid & 15;
    float acc[4][4] = {};
    __syncthreads();
#pragma unroll 1
    for (int kt = 0; kt < 16; ++kt) {
        int k0 = kt * 16;
        int rc = row0 + ra;  // chunk row
        size_t aoff = (size_t)(rc >> 6) * strideB + (size_t)(rc & 63) * 256 + k0 + kq * 4;
        float4 av = *(const float4*)&A[aoff];
        float sc = sS[ra];
        float4 bv = *(const float4*)&Bt[(size_t)(k0 + kb) * 768 + col0 + cq * 4];
        As[kq * 4 + 0][ra] = av.x * sc;
        As[kq * 4 + 1][ra] = av.y * sc;
        As[kq * 4 + 2][ra] = av.z * sc;
        As[kq * 4 + 3][ra] = av.w * sc;
        *(float4*)&Bs[kb][cq * 4] = bv;
        __syncthreads();
#pragma unroll
        for (int kk = 0; kk < 16; ++kk) {
            float4 a4 = *(const float4*)&As[kk][ty * 4];
            float4 b4 = *(const float4*)&Bs[kk][tx * 4];
            float aa[4] = {a4.x, a4.y, a4.z, a4.w};
            float bb[4] = {b4.x, b4.y, b4.z, b4.w};
#pragma unroll
            for (int i = 0; i < 4; ++i)
#pragma unroll
                for (int j = 0; j < 4; ++j)
                    acc[i][j] = fmaf(aa[i], bb[j], acc[i][j]);
        }
        __syncthreads();
    }
#pragma unroll
    for (int i = 0; i < 4; ++i) {
        size_t row = (size_t)row0 + ty * 4 + i;
        *(float4*)&C[row * 768 + col0 + tx * 4] =
            make_float4(acc[i][0], acc[i][1], acc[i][2], acc[i][3]);
    }
}

// ---------- K5: in-place mobius_matvec scaling per (chunk-row, gate) ----------
__global__ __launch_bounds__(256) void kt_mscale(
    float* __restrict__ mx, const float* __restrict__ ax_arr,
    float* __restrict__ uxn, const float* __restrict__ kptr) {
    int lane = threadIdx.x & 63;
    int p = blockIdx.x * 4 + (threadIdx.x >> 6);  // p < 4096*3
    int r = p / 3;
    int g = p - r * 3;
    float k = kptr[0], sk = sqrtf(-k);
    float* ptr = mx + (size_t)r * 768 + g * 256 + lane * 4;
    float4 v = *(const float4*)ptr;
    float n2 = wave_sum(v.x * v.x + v.y * v.y + v.z * v.z + v.w * v.w);
    float nt = sqrtf(n2);
    float mxn = fmaxf(nt, MINN);
    float arg = mxn * ax_arr[r];  // mxn/xn * artan_k(xn)
    float tk = tan_k_(arg, sk);
    float f = tk / mxn;
    v.x *= f; v.y *= f; v.z *= f; v.w *= f;
    *(float4*)ptr = v;
    if (lane == 0) uxn[p] = tk * (nt / mxn);  // ||Ux||
}

// ---------- K6: sequential scan over one chunk, one block per batch elem ----------
__global__ __launch_bounds__(256) void kt_scan(
    const float* __restrict__ Ux, const float* __restrict__ uxn,
    const float* __restrict__ Wt, const float* __restrict__ bias,
    const float* __restrict__ kptr, float* __restrict__ hcar,
    float* __restrict__ outbase, long long stride_b, long long stride_t, int Tc) {
    __shared__ float hy_s[256];
    __shared__ float rh_s[256];
    __shared__ float sred[16];
    const int tid = threadIdx.x;
    const int b = blockIdx.x;
    const float k = kptr[0], sk = sqrtf(-k);

    const float br = bias[tid], bh = bias[256 + tid], bz = bias[512 + tid];
    float4 bn = block_reduce4(make_float4(br * br, bh * bh, bz * bz, 0.f), sred);
    const float bn2r = bn.x, bn2h = bn.y, bn2z = bn.z;

    float h = hcar[b * 256 + tid];  // tangent-space carry
    float* myout = outbase + (size_t)b * stride_b;

    for (int t = 0; t < Tc; ++t) {
        size_t row = (size_t)b * Tc + t;  // compact chunk row
        const float* uxp = Ux + row * 768;
        float uxr = uxp[tid], uxh = uxp[256 + tid], uxz = uxp[512 + tid];
        float unr = uxn[row * 3 + 0], unh = uxn[row * 3 + 1], unz = uxn[row * 3 + 2];

        // ---- expmap0(h) ----
        float4 rA = block_reduce4(make_float4(h * h, 0.f, 0.f, 0.f), sred);
        float hn = sqrtf(rA.x);
        float nrm = fmaxf(hn, MINN);
        float tk0 = tan_k_(nrm, sk);
        float hyv = tk0 / nrm * h;
        float xnh = fmaxf(tk0 * (hn / nrm), MINN);
        float axh = artan_k_(xnh, sk) / xnh;
        hy_s[tid] = hyv;
        __syncthreads();

        // ---- stage-1 matvec: mr = W_hr@hy, mz = W_hz@hy ----
        float mr = 0.f, mz = 0.f;
#pragma unroll 8
        for (int i = 0; i < 256; ++i) {
            float s = hy_s[i];
            mr = fmaf(s, Wt[i * 768 + tid], mr);
            mz = fmaf(s, Wt[i * 768 + 512 + tid], mz);
        }
        float4 rB = block_reduce4(make_float4(mr * mr, mz * mz, hyv * hyv, 0.f), sred);
        float hy2 = rB.z;
        float mxnr = fmaxf(sqrtf(rB.x), MINN), mxnz = fmaxf(sqrtf(rB.y), MINN);
        float tkr = tan_k_(mxnr * axh, sk), tkz = tan_k_(mxnz * axh, sk);
        float whr = tkr / mxnr * mr, whz = tkz / mxnz * mz;
        float x2r = tkr * tkr, x2z = tkz * tkz;
        float y2r = unr * unr, y2z = unz * unz;
        // c1 = mobius_add(Wh, Ux)
        float4 rC = block_reduce4(make_float4(whr * uxr, whz * uxz, 0.f, 0.f), sred);
        float c1r = madd_c(whr, uxr, x2r, y2r, rC.x, k);
        float c1z = madd_c(whz, uxz, x2z, y2z, rC.y, k);
        // c2 = mobius_add(c1, bias)
        float4 rD = block_reduce4(make_float4(c1r * c1r, c1r * br, c1z * c1z, c1z * bz), sred);
        float c2r = madd_c(c1r, br, rD.x, bn2r, rD.y, k);
        float c2z = madd_c(c1z, bz, rD.z, bn2z, rD.w, k);
        // logmap0 -> sigmoid
        float4 rE = block_reduce4(make_float4(c2r * c2r, c2z * c2z, 0.f, 0.f), sred);
        float ynr = fmaxf(sqrtf(rE.x), MINN), ynz = fmaxf(sqrtf(rE.y), MINN);
        float lr = artan_k_(ynr, sk) / ynr * c2r;
        float lz = artan_k_(ynz, sk) / ynz * c2z;
        float r_t = 1.f / (1.f + expf(-lr));
        float z_t = 1.f / (1.f + expf(-lz));

        // ---- rh = mobius_pointwise_mul(r_t, hy) ----
        float wx = r_t * hyv;
        float4 rF = block_reduce4(make_float4(wx * wx, 0.f, 0.f, 0.f), sred);
        float wxt = sqrtf(rF.x);
        float wxn = fmaxf(wxt, MINN);
        float tkw = tan_k_(wxn * axh, sk);
        float rhv = tkw / wxn * wx;
        float rhn = tkw * (wxt / wxn);  // ||rh||
        rh_s[tid] = rhv;
        __syncthreads();

        // ---- stage-2 matvec: mh = W_hh_@rh ----
        float mh = 0.f;
#pragma unroll 8
        for (int i = 0; i < 256; ++i)
            mh = fmaf(rh_s[i], Wt[i * 768 + 256 + tid], mh);
        float4 rG = block_reduce4(make_float4(mh * mh, 0.f, 0.f, 0.f), sred);
        float mxnh = fmaxf(sqrtf(rG.x), MINN);
        float xnrh = fmaxf(rhn, MINN);
        float axrh = artan_k_(xnrh, sk) / xnrh;
        float tkh = tan_k_(mxnh * axrh, sk);
        float whh = tkh / mxnh * mh;
        float x2h = tkh * tkh, y2h = unh * unh;
        float4 rH = block_reduce4(make_float4(whh * uxh, 0.f, 0.f, 0.f), sred);
        float c1h = madd_c(whh, uxh, x2h, y2h, rH.x, k);
        float4 rI = block_reduce4(make_float4(c1h * c1h, c1h * bh, 0.f, 0.f), sred);
        float htl = madd_c(c1h, bh, rI.x, bn2h, rI.y, k);  // h_tilde

        // ---- delta = mobius_add(-hy, h_tilde) ----
        float4 rJ = block_reduce4(make_float4(htl * htl, hyv * htl, 0.f, 0.f), sred);
        float delta = madd_c(-hyv, htl, hy2, rJ.x, -rJ.y, k);

        // ---- zd = mobius_pointwise_mul(z_t, delta) ----
        float wz = z_t * delta;
        float4 rK = block_reduce4(make_float4(delta * delta, wz * wz, 0.f, 0.f), sred);
        float dn = sqrtf(rK.x), dnc = fmaxf(dn, MINN);
        float axd = artan_k_(dnc, sk) / dnc;
        float wzt = sqrtf(rK.y), wznc = fmaxf(wzt, MINN);
        float tkzd = tan_k_(wznc * axd, sk);
        float zd = tkzd / wznc * wz;
        float zdn = tkzd * (wzt / wznc);
        float zdn2 = zdn * zdn;

        // ---- h_new = mobius_add(hy, zd); out = logmap0(h_new) ----
        float4 rL = block_reduce4(make_float4(hyv * zd, 0.f, 0.f, 0.f), sred);
        float hnew = madd_c(hyv, zd, hy2, zdn2, rL.x, k);
        float4 rM = block_reduce4(make_float4(hnew * hnew, 0.f, 0.f, 0.f), sred);
        float yn = fmaxf(sqrtf(rM.x), MINN);
        float outv = artan_k_(yn, sk) / yn * hnew;

        myout[(size_t)t * stride_t + tid] = outv;
        h = outv;
    }
    hcar[b * 256 + tid] = h;
}

// ---------- host launcher ----------
extern "C" void kernel_launch(void* const* d_in, const int* in_sizes, int n_in,
                              void* d_out, int out_size, void* d_ws, size_t ws_size,
                              hipStream_t stream) {
    const float* x    = (const float*)d_in[0];
    const float* kptr = (const float*)d_in[1];
    const float* h0   = (const float*)d_in[2];
    const float* wih0 = (const float*)d_in[3];
    const float* whh0 = (const float*)d_in[4];
    const float* b0   = (const float*)d_in[5];
    const float* wih1 = (const float*)d_in[6];
    const float* whh1 = (const float*)d_in[7];
    const float* b1   = (const float*)d_in[8];
    float* out = (float*)d_out;
    float* ws  = (float*)d_ws;

    const int B = 64, T = 1024, H = 256;
    const int CT = 64, NC = 16;        // T = CT*NC
    const int RC = B * CT;             // 4096 chunk rows

    // ws layout (floats): total 8,200,192 (~31.3 MiB)
    float* wt_ih0 = ws;
    float* wt_hh0 = wt_ih0 + 196608;
    float* wt_ih1 = wt_hh0 + 196608;
    float* wt_hh1 = wt_ih1 + 196608;
    float* hcar   = wt_hh1 + 196608;          // 2*B*H = 32768
    float* s0     = hcar + 32768;             // RC
    float* ax0    = s0 + RC;
    float* s1     = ax0 + RC;
    float* ax1    = s1 + RC;
    float* uxn0   = ax1 + RC;                 // 3*RC
    float* uxn1   = uxn0 + 3 * RC;
    float* out0c  = uxn1 + 3 * RC;            // RC*H = 1,048,576
    float* mx0    = out0c + (size_t)RC * H;   // RC*768
    float* mx1    = mx0 + (size_t)RC * 768;   // RC*768

    float* hcar0 = hcar;
    float* hcar1 = hcar + (size_t)B * H;

    dim3 blk(256);
    kt_transpose<<<dim3(3072), blk, 0, stream>>>(wih0, whh0, wih1, whh1,
                                                 wt_ih0, wt_hh0, wt_ih1, wt_hh1);
    kt_init<<<dim3(128), blk, 0, stream>>>(h0, hcar);

    const long long sbx = (long long)T * 256;   // x row stride per batch elem
    const long long sbc = (long long)CT * 256;  // compact chunk stride per batch elem

    for (int c = 0; c < NC; ++c) {
        const float* xc = x + (size_t)c * CT * 256;
        // ---- layer 0, chunk c ----
        kt_rowscale<<<dim3(RC / 4), blk, 0, stream>>>(xc, sbx, s0, ax0, kptr, 0);
        kt_gemm<<<dim3(12, RC / 64), blk, 0, stream>>>(xc, sbx, s0, wt_ih0, mx0);
        kt_mscale<<<dim3(RC * 3 / 4), blk, 0, stream>>>(mx0, ax0, uxn0, kptr);
        kt_scan<<<dim3(B), blk, 0, stream>>>(mx0, uxn0, wt_hh0, b0, kptr, hcar0,
                                             out0c, sbc, 256LL, CT);
        // ---- layer 1, chunk c ----
        kt_rowscale<<<dim3(RC / 4), blk, 0, stream>>>(out0c, sbc, s1, ax1, kptr, 1);
        kt_gemm<<<dim3(12, RC / 64), blk, 0, stream>>>(out0c, sbc, s1, wt_ih1, mx1);
        kt_mscale<<<dim3(RC * 3 / 4), blk, 0, stream>>>(mx1, ax1, uxn1, kptr);
        kt_scan<<<dim3(B), blk, 0, stream>>>(mx1, uxn1, wt_hh1, b1, kptr, hcar1,
                                             out + (size_t)c * CT * B * H,
                                             256LL, (long long)B * H, CT);
    }
    kt_final<<<dim3(128), blk, 0, stream>>>(hcar, out + (size_t)T * B * H);
}

// Round 3
// 22911.032 us; speedup vs baseline: 1.8255x; 1.8255x over previous
//
#include <hip/hip_runtime.h>
#include <cstdint>
#include <cstddef>

#define MINN 1e-15f
#define EPSA 1e-7f

typedef _Float16 half_t;
typedef _Float16 half2_t __attribute__((ext_vector_type(2)));

// ---------- device helpers ----------
__device__ __forceinline__ float tan_k_(float u, float sk) {
    float a = fminf(fmaxf(sk * u, -15.f), 15.f);
    return tanhf(a) / sk;
}
__device__ __forceinline__ float artan_k_(float u, float sk) {
    float a = fminf(fmaxf(sk * u, -1.f + EPSA), 1.f - EPSA);
    return atanhf(a) / sk;
}
__device__ __forceinline__ float wave_sum(float v) {
#pragma unroll
    for (int off = 32; off; off >>= 1) v += __shfl_xor(v, off, 64);
    return v;
}
// f16 pair dot-accumulate: acc += a.h0*b.h0 + a.h1*b.h1 (f32 accum)
__device__ __forceinline__ float dot2acc(uint32_t w, uint32_t h, float acc) {
#if defined(__has_builtin) && __has_builtin(__builtin_amdgcn_fdot2)
    return __builtin_amdgcn_fdot2(__builtin_bit_cast(half2_t, w),
                                  __builtin_bit_cast(half2_t, h), acc, false);
#else
    half2_t a = __builtin_bit_cast(half2_t, w);
    half2_t b = __builtin_bit_cast(half2_t, h);
    acc = fmaf((float)a[0], (float)b[0], acc);
    return fmaf((float)a[1], (float)b[1], acc);
#endif
}
// block(512)-wide reduce of N values, broadcast result to all threads.
template <int N>
__device__ __forceinline__ void bred(float* v, float* redbuf, int tid) {
#pragma unroll
    for (int n = 0; n < N; ++n) {
#pragma unroll
        for (int off = 32; off; off >>= 1) v[n] += __shfl_xor(v[n], off, 64);
    }
    int wave = tid >> 6, lane = tid & 63;
    __syncthreads();  // protect redbuf from previous use
#pragma unroll
    for (int n = 0; n < N; ++n)
        if (lane == n) redbuf[n * 8 + wave] = v[n];
    __syncthreads();
#pragma unroll
    for (int n = 0; n < N; ++n) {
        float4 a = *(float4*)&redbuf[n * 8];
        float4 b = *(float4*)&redbuf[n * 8 + 4];
        v[n] = ((a.x + a.y) + (a.z + a.w)) + ((b.x + b.y) + (b.z + b.w));
    }
}

// ---------- K1: transpose 2 ih weight matrices [768x256] -> [256x768] ----------
__global__ __launch_bounds__(256) void kt_transpose(
    const float* __restrict__ a0, const float* __restrict__ a1,
    float* __restrict__ o0, float* __restrict__ o1) {
    int idx = blockIdx.x * 256 + threadIdx.x;  // 2*196608 total
    int m = idx / 196608, rem = idx % 196608;
    int j = rem >> 8, kk = rem & 255;
    const float* in = (m == 0) ? a0 : a1;
    float* outp     = (m == 0) ? o0 : o1;
    outp[kk * 768 + j] = in[j * 256 + kk];
}

// ---------- prep1: pack stage-1 (W_hr,W_hz) f16 per-thread fragments ----------
// For layer l, thread t512 (jj=t512&127, q=t512>>7), reg m (o=m>>5,i2l=m&31):
//   j = jj + (o&1)*128 ; gate: o<2 -> r (row j), else z (row 512+j)
//   i = q*64 + 2*i2l ; value = half2(whh[row][i], whh[row][i+1])
// stored at u32 index (m>>2)*2048 + t512*4 + (m&3)  (uint4-coalesced loads)
__global__ __launch_bounds__(256) void kt_prep1(
    const float* __restrict__ whh0, const float* __restrict__ whh1,
    uint32_t* __restrict__ p0, uint32_t* __restrict__ p1) {
    int idx = blockIdx.x * 256 + threadIdx.x;  // 131072
    int l = idx >> 16, e = idx & 65535;
    int r4 = e >> 11, rem = e & 2047;
    int t512 = rem >> 2, m = r4 * 4 + (rem & 3);
    int o = m >> 5, i2l = m & 31;
    int jj = t512 & 127, q = t512 >> 7;
    int j = jj + ((o & 1) << 7);
    int row = (o < 2) ? j : (512 + j);
    int i = q * 64 + 2 * i2l;
    const float* w = l ? whh1 : whh0;
    half2_t hv;
    hv[0] = (half_t)w[row * 256 + i];
    hv[1] = (half_t)w[row * 256 + i + 1];
    (l ? p1 : p0)[e] = __builtin_bit_cast(uint32_t, hv);
}

// ---------- prep2: pack stage-2 (W_hh_) f16 [i2][j] half2 ----------
__global__ __launch_bounds__(256) void kt_prep2(
    const float* __restrict__ whh0, const float* __restrict__ whh1,
    uint32_t* __restrict__ p0, uint32_t* __restrict__ p1) {
    int idx = blockIdx.x * 256 + threadIdx.x;  // 65536
    int l = idx >> 15, e = idx & 32767;
    int i2 = e >> 8, j = e & 255;
    const float* w = l ? whh1 : whh0;
    half2_t hv;
    hv[0] = (half_t)w[(256 + j) * 256 + 2 * i2];
    hv[1] = (half_t)w[(256 + j) * 256 + 2 * i2 + 1];
    (l ? p1 : p0)[e] = __builtin_bit_cast(uint32_t, hv);
}

// ---------- init / final ----------
__global__ __launch_bounds__(256) void kt_init(
    const float* __restrict__ h0, float* __restrict__ hcar) {
    int i = blockIdx.x * 256 + threadIdx.x;
    hcar[i] = h0[i];
}
__global__ __launch_bounds__(256) void kt_final(
    const float* __restrict__ hcar, float* __restrict__ dst) {
    int i = blockIdx.x * 256 + threadIdx.x;
    dst[i] = hcar[i];
}

// ---------- rowscale / gemm / mscale: unchanged from round 2 ----------
__global__ __launch_bounds__(256) void kt_rowscale(
    const float* __restrict__ src, long long strideB,
    float* __restrict__ s_arr, float* __restrict__ ax_arr,
    const float* __restrict__ kptr, int mode) {
    int lane = threadIdx.x & 63;
    int r = blockIdx.x * 4 + (threadIdx.x >> 6);
    float k = kptr[0], sk = sqrtf(-k);
    size_t off = (size_t)(r >> 6) * strideB + (size_t)(r & 63) * 256 + lane * 4;
    float4 v = *(const float4*)&src[off];
    float n2 = wave_sum(v.x * v.x + v.y * v.y + v.z * v.z + v.w * v.w);
    float n = sqrtf(n2);
    float s, xn;
    if (mode == 0) {
        float nrm = fmaxf(n, MINN);
        float tk = tan_k_(nrm, sk);
        s = tk / nrm;
        xn = fmaxf(tk * (n / nrm), MINN);
    } else {
        s = 1.f;
        xn = fmaxf(n, MINN);
    }
    float ax = artan_k_(xn, sk) / xn;
    if (lane == 0) { s_arr[r] = s; ax_arr[r] = ax; }
}

__global__ __launch_bounds__(256) void kt_gemm(
    const float* __restrict__ A, long long strideB,
    const float* __restrict__ s_arr,
    const float* __restrict__ Bt, float* __restrict__ C) {
    __shared__ float As[16][68];
    __shared__ float Bs[16][68];
    __shared__ float sS[64];
    int tid = threadIdx.x;
    int row0 = blockIdx.y * 64, col0 = blockIdx.x * 64;
    if (tid < 64) sS[tid] = s_arr[row0 + tid];
    int ty = tid >> 4, tx = tid & 15;
    int ra = tid >> 2, kq = tid & 3;
    int kb = tid >> 4, cq = tid & 15;
    float acc[4][4] = {};
    __syncthreads();
#pragma unroll 1
    for (int kt = 0; kt < 16; ++kt) {
        int k0 = kt * 16;
        int rc = row0 + ra;
        size_t aoff = (size_t)(rc >> 6) * strideB + (size_t)(rc & 63) * 256 + k0 + kq * 4;
        float4 av = *(const float4*)&A[aoff];
        float sc = sS[ra];
        float4 bv = *(const float4*)&Bt[(size_t)(k0 + kb) * 768 + col0 + cq * 4];
        As[kq * 4 + 0][ra] = av.x * sc;
        As[kq * 4 + 1][ra] = av.y * sc;
        As[kq * 4 + 2][ra] = av.z * sc;
        As[kq * 4 + 3][ra] = av.w * sc;
        *(float4*)&Bs[kb][cq * 4] = bv;
        __syncthreads();
#pragma unroll
        for (int kk = 0; kk < 16; ++kk) {
            float4 a4 = *(const float4*)&As[kk][ty * 4];
            float4 b4 = *(const float4*)&Bs[kk][tx * 4];
            float aa[4] = {a4.x, a4.y, a4.z, a4.w};
            float bb[4] = {b4.x, b4.y, b4.z, b4.w};
#pragma unroll
            for (int i = 0; i < 4; ++i)
#pragma unroll
                for (int j = 0; j < 4; ++j)
                    acc[i][j] = fmaf(aa[i], bb[j], acc[i][j]);
        }
        __syncthreads();
    }
#pragma unroll
    for (int i = 0; i < 4; ++i) {
        size_t row = (size_t)row0 + ty * 4 + i;
        *(float4*)&C[row * 768 + col0 + tx * 4] =
            make_float4(acc[i][0], acc[i][1], acc[i][2], acc[i][3]);
    }
}

__global__ __launch_bounds__(256) void kt_mscale(
    float* __restrict__ mx, const float* __restrict__ ax_arr,
    float* __restrict__ uxn, const float* __restrict__ kptr) {
    int lane = threadIdx.x & 63;
    int p = blockIdx.x * 4 + (threadIdx.x >> 6);
    int r = p / 3;
    int g = p - r * 3;
    float k = kptr[0], sk = sqrtf(-k);
    float* ptr = mx + (size_t)r * 768 + g * 256 + lane * 4;
    float4 v = *(const float4*)ptr;
    float n2 = wave_sum(v.x * v.x + v.y * v.y + v.z * v.z + v.w * v.w);
    float nt = sqrtf(n2);
    float mxn = fmaxf(nt, MINN);
    float arg = mxn * ax_arr[r];
    float tk = tan_k_(arg, sk);
    float f = tk / mxn;
    v.x *= f; v.y *= f; v.z *= f; v.w *= f;
    *(float4*)ptr = v;
    if (lane == 0) uxn[p] = tk * (nt / mxn);
}

// ---------- K6: persistent-weight scan, one block(512) per batch elem ----------
__global__ __launch_bounds__(512, 2) void kt_scan(
    const float* __restrict__ Ux, const float* __restrict__ uxn,
    const uint32_t* __restrict__ w1pk, const uint32_t* __restrict__ whh2g,
    const float* __restrict__ bias, const float* __restrict__ kptr,
    float* __restrict__ hcar, float* __restrict__ outbase,
    long long stride_b, long long stride_t, int Tc) {
    __shared__ uint4 whhS[8192];       // 128 KiB: W_hh_ f16, [i2-quad][j]
    __shared__ uint32_t hy2S[128];     // hy as 128 half2
    __shared__ uint32_t rh2S[128];     // rh as 128 half2
    __shared__ float psum[2560];       // [512 outputs][5-pad] partials
    __shared__ float redbuf[96];

    const int tid = threadIdx.x;
    const int bb = blockIdx.x;
    const int jj = tid & 127, q = tid >> 7;
    const bool owner = (tid < 256);
    const int j = tid;  // owner's output index (valid when owner)
    const float k = kptr[0], sk = sqrtf(-k);

    // stage-2 weights -> LDS
    for (int idx = tid; idx < 32768; idx += 512) {
        uint32_t v = whh2g[idx];
        int i2 = idx >> 8, col = idx & 255;
        ((uint32_t*)whhS)[((i2 >> 2) * 256 + col) * 4 + (i2 & 3)] = v;
    }
    // stage-1 weights -> registers (128 u32 = 256 f16)
    uint32_t w1[128];
    {
        const uint4* wp = (const uint4*)w1pk;  // [32][512] uint4
#pragma unroll
        for (int r4 = 0; r4 < 32; ++r4) {
            uint4 v = wp[r4 * 512 + tid];
            w1[4 * r4 + 0] = v.x; w1[4 * r4 + 1] = v.y;
            w1[4 * r4 + 2] = v.z; w1[4 * r4 + 3] = v.w;
        }
    }

    float br = 0.f, bh = 0.f, bz = 0.f, h = 0.f;
    if (owner) {
        br = bias[j]; bh = bias[256 + j]; bz = bias[512 + j];
        h = hcar[bb * 256 + j];
    }
    float v4[4] = {br * br, bh * bh, bz * bz, h * h};
    bred<4>(v4, redbuf, tid);
    const float bn2r = v4[0], bn2h = v4[1], bn2z = v4[2];
    float S_h2 = v4[3];

    float* myout = outbase + (size_t)bb * stride_b;

    for (int t = 0; t < Tc; ++t) {
        size_t row = (size_t)bb * Tc + t;
        // step-scope owner state
        float uxr = 0.f, uxh = 0.f, uxz = 0.f, unr = 0.f, unh = 0.f, unz = 0.f;
        float hy = 0.f, chy = 0.f, axh = 0.f, Shy2 = 0.f;
        float r_t = 0.f, z_t = 0.f, wx = 0.f, rhn = 0.f;
        float S_ubh = 0.f, S_huxh = 0.f, S_hbh = 0.f;
        float wz = 0.f, Sdelta2 = 0.f;

        if (owner) {
            const float* uxp = Ux + row * 768;
            uxr = uxp[j]; uxh = uxp[256 + j]; uxz = uxp[512 + j];
            unr = uxn[row * 3 + 0]; unh = uxn[row * 3 + 1]; unz = uxn[row * 3 + 2];
            // expmap0(h): all scalars from carried S_h2
            float hn = sqrtf(S_h2);
            float nrm = fmaxf(hn, MINN);
            float tk0 = tan_k_(nrm, sk);
            chy = tk0 / nrm;
            hy = chy * h;
            Shy2 = chy * chy * S_h2;
            float xnh = fmaxf(tk0 * (hn / nrm), MINN);
            axh = artan_k_(xnh, sk) / xnh;
            ((half_t*)hy2S)[j] = (half_t)hy;
        }
        __syncthreads();  // B1: hy ready

        // ---- stage-1 matvec (r,z): 4 partial outputs per thread ----
        {
            uint32_t hv[32];
            const uint4* hp = (const uint4*)hy2S;
#pragma unroll
            for (int r = 0; r < 8; ++r) {
                uint4 v = hp[q * 8 + r];
                hv[4 * r + 0] = v.x; hv[4 * r + 1] = v.y;
                hv[4 * r + 2] = v.z; hv[4 * r + 3] = v.w;
            }
            float p0 = 0.f, p1 = 0.f, p2 = 0.f, p3 = 0.f;
#pragma unroll
            for (int i = 0; i < 32; ++i) {
                p0 = dot2acc(w1[i], hv[i], p0);
                p1 = dot2acc(w1[32 + i], hv[i], p1);
                p2 = dot2acc(w1[64 + i], hv[i], p2);
                p3 = dot2acc(w1[96 + i], hv[i], p3);
            }
            psum[jj * 5 + q] = p0;
            psum[(jj + 128) * 5 + q] = p1;
            psum[(256 + jj) * 5 + q] = p2;
            psum[(384 + jj) * 5 + q] = p3;
        }
        __syncthreads();  // B2: stage-1 partials ready

        float vr[11] = {0.f, 0.f, 0.f, 0.f, 0.f, 0.f, 0.f, 0.f, 0.f, 0.f, 0.f};
        float mr = 0.f, mz = 0.f;
        if (owner) {
            mr = psum[j * 5] + psum[j * 5 + 1] + psum[j * 5 + 2] + psum[j * 5 + 3];
            mz = psum[(256 + j) * 5] + psum[(256 + j) * 5 + 1] +
                 psum[(256 + j) * 5 + 2] + psum[(256 + j) * 5 + 3];
            vr[0] = mr * mr;  vr[1] = mz * mz;
            vr[2] = mr * uxr; vr[3] = mz * uxz;
            vr[4] = mr * br;  vr[5] = mz * bz;
            vr[6] = uxr * br; vr[7] = uxh * bh; vr[8] = uxz * bz;
            vr[9] = h * uxh;  vr[10] = h * bh;
        }
        bred<11>(vr, redbuf, tid);

        float v1[1] = {0.f};
        if (owner) {
            float S_mr2 = vr[0], S_mz2 = vr[1], S_mru = vr[2], S_mzu = vr[3];
            float S_mrb = vr[4], S_mzb = vr[5], S_ubr = vr[6];
            S_ubh = vr[7];
            float S_ubz = vr[8];
            S_huxh = vr[9]; S_hbh = vr[10];
            // --- r gate ---
            {
                float mxn = fmaxf(sqrtf(S_mr2), MINN);
                float tk = tan_k_(mxn * axh, sk);
                float f = tk / mxn;
                float x2 = f * f * S_mr2, y2 = unr * unr, xy = f * S_mru;
                float a = 1.f - 2.f * k * xy - k * y2;
                float bq = 1.f + k * x2;
                float d = fmaxf(1.f - 2.f * k * xy + k * k * x2 * y2, MINN);
                float c1 = (a * f * mr + bq * uxr) / d;
                float Sc12 = (a * a * x2 + 2.f * a * bq * xy + bq * bq * y2) / (d * d);
                float Sc1b = (a * f * S_mrb + bq * S_ubr) / d;
                float g = 1.f - 2.f * k * Sc1b - k * bn2r;
                float dl = 1.f + k * Sc12;
                float e = fmaxf(1.f - 2.f * k * Sc1b + k * k * Sc12 * bn2r, MINN);
                float c2 = (g * c1 + dl * br) / e;
                float Sc22 = (g * g * Sc12 + 2.f * g * dl * Sc1b + dl * dl * bn2r) / (e * e);
                float yn = fmaxf(sqrtf(Sc22), MINN);
                float lr = artan_k_(yn, sk) / yn * c2;
                r_t = 1.f / (1.f + expf(-lr));
            }
            // --- z gate ---
            {
                float mxn = fmaxf(sqrtf(S_mz2), MINN);
                float tk = tan_k_(mxn * axh, sk);
                float f = tk / mxn;
                float x2 = f * f * S_mz2, y2 = unz * unz, xy = f * S_mzu;
                float a = 1.f - 2.f * k * xy - k * y2;
                float bq = 1.f + k * x2;
                float d = fmaxf(1.f - 2.f * k * xy + k * k * x2 * y2, MINN);
                float c1 = (a * f * mz + bq * uxz) / d;
                float Sc12 = (a * a * x2 + 2.f * a * bq * xy + bq * bq * y2) / (d * d);
                float Sc1b = (a * f * S_mzb + bq * S_ubz) / d;
                float g = 1.f - 2.f * k * Sc1b - k * bn2z;
                float dl = 1.f + k * Sc12;
                float e = fmaxf(1.f - 2.f * k * Sc1b + k * k * Sc12 * bn2z, MINN);
                float c2 = (g * c1 + dl * bz) / e;
                float Sc22 = (g * g * Sc12 + 2.f * g * dl * Sc1b + dl * dl * bn2z) / (e * e);
                float yn = fmaxf(sqrtf(Sc22), MINN);
                float lz = artan_k_(yn, sk) / yn * c2;
                z_t = 1.f / (1.f + expf(-lz));
            }
            wx = r_t * hy;
            v1[0] = wx * wx;
        }
        bred<1>(v1, redbuf, tid);
        float S_wx2 = v1[0];

        if (owner) {
            float wxt = sqrtf(S_wx2);
            float wxn = fmaxf(wxt, MINN);
            float tkw = tan_k_(wxn * axh, sk);
            float fw = tkw / wxn;
            rhn = tkw * (wxt / wxn);
            ((half_t*)rh2S)[j] = (half_t)(fw * wx);
        }
        __syncthreads();  // B5: rh ready

        // ---- stage-2 matvec (h gate) from LDS weights ----
        {
            uint32_t rv[32];
            const uint4* rp = (const uint4*)rh2S;
#pragma unroll
            for (int r = 0; r < 8; ++r) {
                uint4 v = rp[q * 8 + r];
                rv[4 * r + 0] = v.x; rv[4 * r + 1] = v.y;
                rv[4 * r + 2] = v.z; rv[4 * r + 3] = v.w;
            }
            float p0 = 0.f, p1 = 0.f;
#pragma unroll
            for (int tq = 0; tq < 8; ++tq) {
                uint4 wv = whhS[(q * 8 + tq) * 256 + jj];
                p0 = dot2acc(wv.x, rv[4 * tq + 0], p0);
                p0 = dot2acc(wv.y, rv[4 * tq + 1], p0);
                p0 = dot2acc(wv.z, rv[4 * tq + 2], p0);
                p0 = dot2acc(wv.w, rv[4 * tq + 3], p0);
            }
#pragma unroll
            for (int tq = 0; tq < 8; ++tq) {
                uint4 wv = whhS[(q * 8 + tq) * 256 + jj + 128];
                p1 = dot2acc(wv.x, rv[4 * tq + 0], p1);
                p1 = dot2acc(wv.y, rv[4 * tq + 1], p1);
                p1 = dot2acc(wv.z, rv[4 * tq + 2], p1);
                p1 = dot2acc(wv.w, rv[4 * tq + 3], p1);
            }
            psum[jj * 5 + q] = p0;
            psum[(128 + jj) * 5 + q] = p1;
        }
        __syncthreads();  // B6: stage-2 partials ready

        float v4b[4] = {0.f, 0.f, 0.f, 0.f};
        float mh = 0.f;
        if (owner) {
            mh = psum[j * 5] + psum[j * 5 + 1] + psum[j * 5 + 2] + psum[j * 5 + 3];
            v4b[0] = mh * mh; v4b[1] = mh * uxh; v4b[2] = mh * bh; v4b[3] = hy * mh;
        }
        bred<4>(v4b, redbuf, tid);

        float v2[2] = {0.f, 0.f};
        if (owner) {
            float S_mh2 = v4b[0], S_mhu = v4b[1], S_mhb = v4b[2], S_hymh = v4b[3];
            float xnrh = fmaxf(rhn, MINN);
            float axrh = artan_k_(xnrh, sk) / xnrh;
            float mxn = fmaxf(sqrtf(S_mh2), MINN);
            float tk = tan_k_(mxn * axrh, sk);
            float f = tk / mxn;
            float x2 = f * f * S_mh2, y2 = unh * unh, xy = f * S_mhu;
            float a = 1.f - 2.f * k * xy - k * y2;
            float bq = 1.f + k * x2;
            float d = fmaxf(1.f - 2.f * k * xy + k * k * x2 * y2, MINN);
            float c1 = (a * f * mh + bq * uxh) / d;
            float Sc12 = (a * a * x2 + 2.f * a * bq * xy + bq * bq * y2) / (d * d);
            float Sc1b = (a * f * S_mhb + bq * S_ubh) / d;
            float S_hyc1 = (a * f * S_hymh + bq * chy * S_huxh) / d;
            float g = 1.f - 2.f * k * Sc1b - k * bn2h;
            float dl = 1.f + k * Sc12;
            float e = fmaxf(1.f - 2.f * k * Sc1b + k * k * Sc12 * bn2h, MINN);
            float htl = (g * c1 + dl * bh) / e;
            float Shtl2 = (g * g * Sc12 + 2.f * g * dl * Sc1b + dl * dl * bn2h) / (e * e);
            float S_hyhtl = (g * S_hyc1 + dl * chy * S_hbh) / e;
            // delta = mobius_add(-hy, htl): xy_d = -S_hyhtl
            float ad = 1.f + 2.f * k * S_hyhtl - k * Shtl2;
            float bd = 1.f + k * Shy2;
            float dd = fmaxf(1.f + 2.f * k * S_hyhtl + k * k * Shy2 * Shtl2, MINN);
            float delta = (ad * (-hy) + bd * htl) / dd;
            Sdelta2 = (ad * ad * Shy2 - 2.f * ad * bd * S_hyhtl + bd * bd * Shtl2) / (dd * dd);
            wz = z_t * delta;
            v2[0] = wz * wz; v2[1] = hy * wz;
        }
        bred<2>(v2, redbuf, tid);

        if (owner) {
            float S_wz2 = v2[0], S_hywz = v2[1];
            float dnc = fmaxf(sqrtf(Sdelta2), MINN);
            float axd = artan_k_(dnc, sk) / dnc;
            float wzt = sqrtf(S_wz2);
            float wznc = fmaxf(wzt, MINN);
            float tkzd = tan_k_(wznc * axd, sk);
            float fz = tkzd / wznc;
            float zd = fz * wz;
            float zdn2 = fz * fz * S_wz2;
            float S_hyzd = fz * S_hywz;
            float an = 1.f - 2.f * k * S_hyzd - k * zdn2;
            float bn_ = 1.f + k * Shy2;
            float dnn = fmaxf(1.f - 2.f * k * S_hyzd + k * k * Shy2 * zdn2, MINN);
            float hnew = (an * hy + bn_ * zd) / dnn;
            float Shnew2 = (an * an * Shy2 + 2.f * an * bn_ * S_hyzd + bn_ * bn_ * zdn2) / (dnn * dnn);
            float yn = fmaxf(sqrtf(Shnew2), MINN);
            float ayn = artan_k_(yn, sk) / yn;
            float outv = ayn * hnew;
            myout[(size_t)t * stride_t + j] = outv;
            h = outv;
            S_h2 = ayn * ayn * Shnew2;  // ||h||^2 for next step, no reduction
        }
    }
    if (owner) hcar[bb * 256 + j] = h;
}

// ---------- host launcher ----------
extern "C" void kernel_launch(void* const* d_in, const int* in_sizes, int n_in,
                              void* d_out, int out_size, void* d_ws, size_t ws_size,
                              hipStream_t stream) {
    const float* x    = (const float*)d_in[0];
    const float* kptr = (const float*)d_in[1];
    const float* h0   = (const float*)d_in[2];
    const float* wih0 = (const float*)d_in[3];
    const float* whh0 = (const float*)d_in[4];
    const float* b0   = (const float*)d_in[5];
    const float* wih1 = (const float*)d_in[6];
    const float* whh1 = (const float*)d_in[7];
    const float* b1   = (const float*)d_in[8];
    float* out = (float*)d_out;
    float* ws  = (float*)d_ws;

    const int B = 64, T = 1024, H = 256;
    const int CT = 64, NC = 16;
    const int RC = B * CT;  // 4096

    // ws layout (float slots), total ~8.0M floats (~30.5 MiB)
    float* wt_ih0 = ws;
    float* wt_ih1 = wt_ih0 + 196608;
    uint32_t* w1pk0  = (uint32_t*)(wt_ih1 + 196608);  // 65536 u32
    uint32_t* w1pk1  = w1pk0 + 65536;
    uint32_t* whh2g0 = w1pk1 + 65536;                 // 32768 u32
    uint32_t* whh2g1 = whh2g0 + 32768;
    float* hcar  = (float*)(whh2g1 + 32768);          // 32768
    float* s0    = hcar + 32768;                      // 4096
    float* ax0   = s0 + RC;
    float* s1    = ax0 + RC;
    float* ax1   = s1 + RC;
    float* uxn0  = ax1 + RC;                          // 12288
    float* uxn1  = uxn0 + 3 * RC;
    float* out0c = uxn1 + 3 * RC;                     // 1,048,576
    float* mx0   = out0c + (size_t)RC * H;            // 3,145,728
    float* mx1   = mx0 + (size_t)RC * 768;

    float* hcar0 = hcar;
    float* hcar1 = hcar + (size_t)B * H;

    dim3 blk(256);
    kt_transpose<<<dim3(1536), blk, 0, stream>>>(wih0, wih1, wt_ih0, wt_ih1);
    kt_prep1<<<dim3(512), blk, 0, stream>>>(whh0, whh1, w1pk0, w1pk1);
    kt_prep2<<<dim3(256), blk, 0, stream>>>(whh0, whh1, whh2g0, whh2g1);
    kt_init<<<dim3(128), blk, 0, stream>>>(h0, hcar);

    const long long sbx = (long long)T * 256;
    const long long sbc = (long long)CT * 256;

    for (int c = 0; c < NC; ++c) {
        const float* xc = x + (size_t)c * CT * 256;
        // ---- layer 0, chunk c ----
        kt_rowscale<<<dim3(RC / 4), blk, 0, stream>>>(xc, sbx, s0, ax0, kptr, 0);
        kt_gemm<<<dim3(12, RC / 64), blk, 0, stream>>>(xc, sbx, s0, wt_ih0, mx0);
        kt_mscale<<<dim3(RC * 3 / 4), blk, 0, stream>>>(mx0, ax0, uxn0, kptr);
        kt_scan<<<dim3(B), dim3(512), 0, stream>>>(mx0, uxn0, w1pk0, whh2g0, b0, kptr,
                                                   hcar0, out0c, sbc, 256LL, CT);
        // ---- layer 1, chunk c ----
        kt_rowscale<<<dim3(RC / 4), blk, 0, stream>>>(out0c, sbc, s1, ax1, kptr, 1);
        kt_gemm<<<dim3(12, RC / 64), blk, 0, stream>>>(out0c, sbc, s1, wt_ih1, mx1);
        kt_mscale<<<dim3(RC * 3 / 4), blk, 0, stream>>>(mx1, ax1, uxn1, kptr);
        kt_scan<<<dim3(B), dim3(512), 0, stream>>>(mx1, uxn1, w1pk1, whh2g1, b1, kptr,
                                                   hcar1, out + (size_t)c * CT * B * H,
                                                   256LL, (long long)B * H, CT);
    }
    kt_final<<<dim3(128), blk, 0, stream>>>(hcar, out + (size_t)T * B * H);
}

// Round 4
// 12412.963 us; speedup vs baseline: 3.3694x; 1.8457x over previous
//
#include <hip/hip_runtime.h>
#include <cstdint>
#include <cstddef>

#define MINN 1e-15f
#define EPSA 1e-7f

typedef _Float16 half_t;
typedef _Float16 half2_t __attribute__((ext_vector_type(2)));

// ---------- device helpers ----------
__device__ __forceinline__ float tan_k_(float u, float sk) {
    float a = fminf(fmaxf(sk * u, -15.f), 15.f);
    return tanhf(a) / sk;
}
__device__ __forceinline__ float artan_k_(float u, float sk) {
    float a = fminf(fmaxf(sk * u, -1.f + EPSA), 1.f - EPSA);
    return atanhf(a) / sk;
}
__device__ __forceinline__ float wave_sum(float v) {
#pragma unroll
    for (int off = 32; off; off >>= 1) v += __shfl_xor(v, off, 64);
    return v;
}
// f16 pair dot-accumulate: acc += a.h0*b.h0 + a.h1*b.h1 (f32 accum)
__device__ __forceinline__ float dot2acc(uint32_t w, uint32_t h, float acc) {
#if defined(__has_builtin) && __has_builtin(__builtin_amdgcn_fdot2)
    return __builtin_amdgcn_fdot2(__builtin_bit_cast(half2_t, w),
                                  __builtin_bit_cast(half2_t, h), acc, false);
#else
    half2_t a = __builtin_bit_cast(half2_t, w);
    half2_t b = __builtin_bit_cast(half2_t, h);
    acc = fmaf((float)a[0], (float)b[0], acc);
    return fmaf((float)a[1], (float)b[1], acc);
#endif
}
// block(512)-wide reduce of N values, broadcast. Double-buffered caller
// scratch: exactly ONE internal barrier (caller guarantees buffer parity
// alternation between consecutive calls).
template <int N>
__device__ __forceinline__ void bredDB(float* v, float* redbuf, int tid) {
#pragma unroll
    for (int n = 0; n < N; ++n) {
#pragma unroll
        for (int off = 32; off; off >>= 1) v[n] += __shfl_xor(v[n], off, 64);
    }
    int wave = tid >> 6, lane = tid & 63;
#pragma unroll
    for (int n = 0; n < N; ++n)
        if (lane == n) redbuf[n * 8 + wave] = v[n];
    __syncthreads();
#pragma unroll
    for (int n = 0; n < N; ++n) {
        float4 a = *(float4*)&redbuf[n * 8];
        float4 b = *(float4*)&redbuf[n * 8 + 4];
        v[n] = ((a.x + a.y) + (a.z + a.w)) + ((b.x + b.y) + (b.z + b.w));
    }
}

// ---------- K1: transpose 2 ih weight matrices [768x256] -> [256x768] ----------
__global__ __launch_bounds__(256) void kt_transpose(
    const float* __restrict__ a0, const float* __restrict__ a1,
    float* __restrict__ o0, float* __restrict__ o1) {
    int idx = blockIdx.x * 256 + threadIdx.x;
    int m = idx / 196608, rem = idx % 196608;
    int j = rem >> 8, kk = rem & 255;
    const float* in = (m == 0) ? a0 : a1;
    float* outp     = (m == 0) ? o0 : o1;
    outp[kk * 768 + j] = in[j * 256 + kk];
}

// ---------- prep1: pack stage-1 (W_hr,W_hz) f16 per-thread fragments ----------
__global__ __launch_bounds__(256) void kt_prep1(
    const float* __restrict__ whh0, const float* __restrict__ whh1,
    uint32_t* __restrict__ p0, uint32_t* __restrict__ p1) {
    int idx = blockIdx.x * 256 + threadIdx.x;  // 131072
    int l = idx >> 16, e = idx & 65535;
    int r4 = e >> 11, rem = e & 2047;
    int t512 = rem >> 2, m = r4 * 4 + (rem & 3);
    int o = m >> 5, i2l = m & 31;
    int jj = t512 & 127, q = t512 >> 7;
    int j = jj + ((o & 1) << 7);
    int row = (o < 2) ? j : (512 + j);
    int i = q * 64 + 2 * i2l;
    const float* w = l ? whh1 : whh0;
    half2_t hv;
    hv[0] = (half_t)w[row * 256 + i];
    hv[1] = (half_t)w[row * 256 + i + 1];
    (l ? p1 : p0)[e] = __builtin_bit_cast(uint32_t, hv);
}

// ---------- prep2: pack stage-2 (W_hh_) f16 [i2][j] half2 ----------
__global__ __launch_bounds__(256) void kt_prep2(
    const float* __restrict__ whh0, const float* __restrict__ whh1,
    uint32_t* __restrict__ p0, uint32_t* __restrict__ p1) {
    int idx = blockIdx.x * 256 + threadIdx.x;  // 65536
    int l = idx >> 15, e = idx & 32767;
    int i2 = e >> 8, j = e & 255;
    const float* w = l ? whh1 : whh0;
    half2_t hv;
    hv[0] = (half_t)w[(256 + j) * 256 + 2 * i2];
    hv[1] = (half_t)w[(256 + j) * 256 + 2 * i2 + 1];
    (l ? p1 : p0)[e] = __builtin_bit_cast(uint32_t, hv);
}

// ---------- init / final ----------
__global__ __launch_bounds__(256) void kt_init(
    const float* __restrict__ h0, float* __restrict__ hcar) {
    int i = blockIdx.x * 256 + threadIdx.x;
    hcar[i] = h0[i];
}
__global__ __launch_bounds__(256) void kt_final(
    const float* __restrict__ hcar, float* __restrict__ dst) {
    int i = blockIdx.x * 256 + threadIdx.x;
    dst[i] = hcar[i];
}

// ---------- rowscale / gemm / mscale ----------
__global__ __launch_bounds__(256) void kt_rowscale(
    const float* __restrict__ src, long long strideB,
    float* __restrict__ s_arr, float* __restrict__ ax_arr,
    const float* __restrict__ kptr, int mode) {
    int lane = threadIdx.x & 63;
    int r = blockIdx.x * 4 + (threadIdx.x >> 6);
    float k = kptr[0], sk = sqrtf(-k);
    size_t off = (size_t)(r >> 6) * strideB + (size_t)(r & 63) * 256 + lane * 4;
    float4 v = *(const float4*)&src[off];
    float n2 = wave_sum(v.x * v.x + v.y * v.y + v.z * v.z + v.w * v.w);
    float n = sqrtf(n2);
    float s, xn;
    if (mode == 0) {
        float nrm = fmaxf(n, MINN);
        float tk = tan_k_(nrm, sk);
        s = tk / nrm;
        xn = fmaxf(tk * (n / nrm), MINN);
    } else {
        s = 1.f;
        xn = fmaxf(n, MINN);
    }
    float ax = artan_k_(xn, sk) / xn;
    if (lane == 0) { s_arr[r] = s; ax_arr[r] = ax; }
}

__global__ __launch_bounds__(256) void kt_gemm(
    const float* __restrict__ A, long long strideB,
    const float* __restrict__ s_arr,
    const float* __restrict__ Bt, float* __restrict__ C) {
    __shared__ float As[16][68];
    __shared__ float Bs[16][68];
    __shared__ float sS[64];
    int tid = threadIdx.x;
    int row0 = blockIdx.y * 64, col0 = blockIdx.x * 64;
    if (tid < 64) sS[tid] = s_arr[row0 + tid];
    int ty = tid >> 4, tx = tid & 15;
    int ra = tid >> 2, kq = tid & 3;
    int kb = tid >> 4, cq = tid & 15;
    float acc[4][4] = {};
    __syncthreads();
#pragma unroll 1
    for (int kt = 0; kt < 16; ++kt) {
        int k0 = kt * 16;
        int rc = row0 + ra;
        size_t aoff = (size_t)(rc >> 6) * strideB + (size_t)(rc & 63) * 256 + k0 + kq * 4;
        float4 av = *(const float4*)&A[aoff];
        float sc = sS[ra];
        float4 bv = *(const float4*)&Bt[(size_t)(k0 + kb) * 768 + col0 + cq * 4];
        As[kq * 4 + 0][ra] = av.x * sc;
        As[kq * 4 + 1][ra] = av.y * sc;
        As[kq * 4 + 2][ra] = av.z * sc;
        As[kq * 4 + 3][ra] = av.w * sc;
        *(float4*)&Bs[kb][cq * 4] = bv;
        __syncthreads();
#pragma unroll
        for (int kk = 0; kk < 16; ++kk) {
            float4 a4 = *(const float4*)&As[kk][ty * 4];
            float4 b4 = *(const float4*)&Bs[kk][tx * 4];
            float aa[4] = {a4.x, a4.y, a4.z, a4.w};
            float bb[4] = {b4.x, b4.y, b4.z, b4.w};
#pragma unroll
            for (int i = 0; i < 4; ++i)
#pragma unroll
                for (int j = 0; j < 4; ++j)
                    acc[i][j] = fmaf(aa[i], bb[j], acc[i][j]);
        }
        __syncthreads();
    }
#pragma unroll
    for (int i = 0; i < 4; ++i) {
        size_t row = (size_t)row0 + ty * 4 + i;
        *(float4*)&C[row * 768 + col0 + tx * 4] =
            make_float4(acc[i][0], acc[i][1], acc[i][2], acc[i][3]);
    }
}

__global__ __launch_bounds__(256) void kt_mscale(
    float* __restrict__ mx, const float* __restrict__ ax_arr,
    float* __restrict__ uxn, const float* __restrict__ kptr) {
    int lane = threadIdx.x & 63;
    int p = blockIdx.x * 4 + (threadIdx.x >> 6);
    int r = p / 3;
    int g = p - r * 3;
    float k = kptr[0], sk = sqrtf(-k);
    float* ptr = mx + (size_t)r * 768 + g * 256 + lane * 4;
    float4 v = *(const float4*)ptr;
    float n2 = wave_sum(v.x * v.x + v.y * v.y + v.z * v.z + v.w * v.w);
    float nt = sqrtf(n2);
    float mxn = fmaxf(nt, MINN);
    float arg = mxn * ax_arr[r];
    float tk = tan_k_(arg, sk);
    float f = tk / mxn;
    v.x *= f; v.y *= f; v.z *= f; v.w *= f;
    *(float4*)ptr = v;
    if (lane == 0) uxn[p] = tk * (nt / mxn);
}

// ---------- K6: persistent-weight scan, dual-role (layer-pipelined) ----------
// Blocks [0, nrole0) run role 0; blocks [nrole0, grid) run role 1.
__global__ __launch_bounds__(512, 1) void kt_scan2(
    const float* __restrict__ Ux_0, const float* __restrict__ uxn_0,
    const uint32_t* __restrict__ w1pk_0, const uint32_t* __restrict__ whh2g_0,
    const float* __restrict__ bias_0, float* __restrict__ hcar_0,
    float* __restrict__ out_0, long long sb_0, long long st_0,
    const float* __restrict__ Ux_1, const float* __restrict__ uxn_1,
    const uint32_t* __restrict__ w1pk_1, const uint32_t* __restrict__ whh2g_1,
    const float* __restrict__ bias_1, float* __restrict__ hcar_1,
    float* __restrict__ out_1, long long sb_1, long long st_1,
    const float* __restrict__ kptr, int Tc, int nrole0) {
    __shared__ uint4 whhS[8192];       // 128 KiB: W_hh_ f16, [i2-quad][j]
    __shared__ uint32_t hy2S[128];     // hy as 128 half2
    __shared__ uint32_t rh2S[128];     // rh as 128 half2
    __shared__ float psum[2560];       // [512 outputs][5-pad] partials
    __shared__ float redbuf[2][96];    // double-buffered bred scratch

    const int tid = threadIdx.x;
    const int role = (blockIdx.x >= nrole0) ? 1 : 0;
    const int bb = role ? (int)blockIdx.x - nrole0 : (int)blockIdx.x;

    const float* Ux      = role ? Ux_1 : Ux_0;
    const float* uxn     = role ? uxn_1 : uxn_0;
    const uint32_t* w1pk = role ? w1pk_1 : w1pk_0;
    const uint32_t* whh2g= role ? whh2g_1 : whh2g_0;
    const float* bias    = role ? bias_1 : bias_0;
    float* hcar          = role ? hcar_1 : hcar_0;
    float* outbase       = role ? out_1 : out_0;
    const long long stride_b = role ? sb_1 : sb_0;
    const long long stride_t = role ? st_1 : st_0;

    const int jj = tid & 127, q = tid >> 7;
    const bool owner = (tid < 256);
    const int j = tid;
    const float k = kptr[0], sk = sqrtf(-k);

    // stage-2 weights -> LDS
    for (int idx = tid; idx < 32768; idx += 512) {
        uint32_t v = whh2g[idx];
        int i2 = idx >> 8, col = idx & 255;
        ((uint32_t*)whhS)[((i2 >> 2) * 256 + col) * 4 + (i2 & 3)] = v;
    }
    // stage-1 weights -> registers (128 u32 = 256 f16)
    uint32_t w1[128];
    {
        const uint4* wp = (const uint4*)w1pk;  // [32][512] uint4
#pragma unroll
        for (int r4 = 0; r4 < 32; ++r4) {
            uint4 v = wp[r4 * 512 + tid];
            w1[4 * r4 + 0] = v.x; w1[4 * r4 + 1] = v.y;
            w1[4 * r4 + 2] = v.z; w1[4 * r4 + 3] = v.w;
        }
    }

    float br = 0.f, bh = 0.f, bz = 0.f, h = 0.f;
    if (owner) {
        br = bias[j]; bh = bias[256 + j]; bz = bias[512 + j];
        h = hcar[bb * 256 + j];
    }
    __syncthreads();  // LDS whhS ready + redbuf clean before first bred
    float v4[4] = {br * br, bh * bh, bz * bz, h * h};
    bredDB<4>(v4, redbuf[0], tid);
    const float bn2r = v4[0], bn2h = v4[1], bn2z = v4[2];
    float S_h2 = v4[3];

    float* myout = outbase + (size_t)bb * stride_b;

    for (int t = 0; t < Tc; ++t) {
        size_t row = (size_t)bb * Tc + t;
        float uxr = 0.f, uxh = 0.f, uxz = 0.f, unr = 0.f, unh = 0.f, unz = 0.f;
        float hy = 0.f, chy = 0.f, axh = 0.f, Shy2 = 0.f;
        float r_t = 0.f, z_t = 0.f, wx = 0.f, rhn = 0.f;
        float S_ubh = 0.f, S_huxh = 0.f, S_hbh = 0.f;
        float wz = 0.f, Sdelta2 = 0.f;

        if (owner) {
            const float* uxp = Ux + row * 768;
            uxr = uxp[j]; uxh = uxp[256 + j]; uxz = uxp[512 + j];
            unr = uxn[row * 3 + 0]; unh = uxn[row * 3 + 1]; unz = uxn[row * 3 + 2];
            float hn = sqrtf(S_h2);
            float nrm = fmaxf(hn, MINN);
            float tk0 = tan_k_(nrm, sk);
            chy = tk0 / nrm;
            hy = chy * h;
            Shy2 = chy * chy * S_h2;
            float xnh = fmaxf(tk0 * (hn / nrm), MINN);
            axh = artan_k_(xnh, sk) / xnh;
            ((half_t*)hy2S)[j] = (half_t)hy;
        }
        __syncthreads();  // B1: hy ready

        // ---- stage-1 matvec (r,z) ----
        {
            uint32_t hv[32];
            const uint4* hp = (const uint4*)hy2S;
#pragma unroll
            for (int r = 0; r < 8; ++r) {
                uint4 v = hp[q * 8 + r];
                hv[4 * r + 0] = v.x; hv[4 * r + 1] = v.y;
                hv[4 * r + 2] = v.z; hv[4 * r + 3] = v.w;
            }
            float p0 = 0.f, p1 = 0.f, p2 = 0.f, p3 = 0.f;
#pragma unroll
            for (int i = 0; i < 32; ++i) {
                p0 = dot2acc(w1[i], hv[i], p0);
                p1 = dot2acc(w1[32 + i], hv[i], p1);
                p2 = dot2acc(w1[64 + i], hv[i], p2);
                p3 = dot2acc(w1[96 + i], hv[i], p3);
            }
            psum[jj * 5 + q] = p0;
            psum[(jj + 128) * 5 + q] = p1;
            psum[(256 + jj) * 5 + q] = p2;
            psum[(384 + jj) * 5 + q] = p3;
        }
        __syncthreads();  // B2: stage-1 partials ready

        float vr[11] = {0.f, 0.f, 0.f, 0.f, 0.f, 0.f, 0.f, 0.f, 0.f, 0.f, 0.f};
        float mr = 0.f, mz = 0.f;
        if (owner) {
            mr = psum[j * 5] + psum[j * 5 + 1] + psum[j * 5 + 2] + psum[j * 5 + 3];
            mz = psum[(256 + j) * 5] + psum[(256 + j) * 5 + 1] +
                 psum[(256 + j) * 5 + 2] + psum[(256 + j) * 5 + 3];
            vr[0] = mr * mr;  vr[1] = mz * mz;
            vr[2] = mr * uxr; vr[3] = mz * uxz;
            vr[4] = mr * br;  vr[5] = mz * bz;
            vr[6] = uxr * br; vr[7] = uxh * bh; vr[8] = uxz * bz;
            vr[9] = h * uxh;  vr[10] = h * bh;
        }
        bredDB<11>(vr, redbuf[0], tid);

        float v1[1] = {0.f};
        if (owner) {
            float S_mr2 = vr[0], S_mz2 = vr[1], S_mru = vr[2], S_mzu = vr[3];
            float S_mrb = vr[4], S_mzb = vr[5], S_ubr = vr[6];
            S_ubh = vr[7];
            float S_ubz = vr[8];
            S_huxh = vr[9]; S_hbh = vr[10];
            {
                float mxn = fmaxf(sqrtf(S_mr2), MINN);
                float tk = tan_k_(mxn * axh, sk);
                float f = tk / mxn;
                float x2 = f * f * S_mr2, y2 = unr * unr, xy = f * S_mru;
                float a = 1.f - 2.f * k * xy - k * y2;
                float bq = 1.f + k * x2;
                float d = fmaxf(1.f - 2.f * k * xy + k * k * x2 * y2, MINN);
                float c1 = (a * f * mr + bq * uxr) / d;
                float Sc12 = (a * a * x2 + 2.f * a * bq * xy + bq * bq * y2) / (d * d);
                float Sc1b = (a * f * S_mrb + bq * S_ubr) / d;
                float g = 1.f - 2.f * k * Sc1b - k * bn2r;
                float dl = 1.f + k * Sc12;
                float e = fmaxf(1.f - 2.f * k * Sc1b + k * k * Sc12 * bn2r, MINN);
                float c2 = (g * c1 + dl * br) / e;
                float Sc22 = (g * g * Sc12 + 2.f * g * dl * Sc1b + dl * dl * bn2r) / (e * e);
                float yn = fmaxf(sqrtf(Sc22), MINN);
                float lr = artan_k_(yn, sk) / yn * c2;
                r_t = 1.f / (1.f + expf(-lr));
            }
            {
                float mxn = fmaxf(sqrtf(S_mz2), MINN);
                float tk = tan_k_(mxn * axh, sk);
                float f = tk / mxn;
                float x2 = f * f * S_mz2, y2 = unz * unz, xy = f * S_mzu;
                float a = 1.f - 2.f * k * xy - k * y2;
                float bq = 1.f + k * x2;
                float d = fmaxf(1.f - 2.f * k * xy + k * k * x2 * y2, MINN);
                float c1 = (a * f * mz + bq * uxz) / d;
                float Sc12 = (a * a * x2 + 2.f * a * bq * xy + bq * bq * y2) / (d * d);
                float Sc1b = (a * f * S_mzb + bq * S_ubz) / d;
                float g = 1.f - 2.f * k * Sc1b - k * bn2z;
                float dl = 1.f + k * Sc12;
                float e = fmaxf(1.f - 2.f * k * Sc1b + k * k * Sc12 * bn2z, MINN);
                float c2 = (g * c1 + dl * bz) / e;
                float Sc22 = (g * g * Sc12 + 2.f * g * dl * Sc1b + dl * dl * bn2z) / (e * e);
                float yn = fmaxf(sqrtf(Sc22), MINN);
                float lz = artan_k_(yn, sk) / yn * c2;
                z_t = 1.f / (1.f + expf(-lz));
            }
            wx = r_t * hy;
            v1[0] = wx * wx;
        }
        bredDB<1>(v1, redbuf[1], tid);
        float S_wx2 = v1[0];

        if (owner) {
            float wxt = sqrtf(S_wx2);
            float wxn = fmaxf(wxt, MINN);
            float tkw = tan_k_(wxn * axh, sk);
            float fw = tkw / wxn;
            rhn = tkw * (wxt / wxn);
            ((half_t*)rh2S)[j] = (half_t)(fw * wx);
        }
        __syncthreads();  // B5: rh ready

        // ---- stage-2 matvec (h gate) from LDS weights ----
        {
            uint32_t rv[32];
            const uint4* rp = (const uint4*)rh2S;
#pragma unroll
            for (int r = 0; r < 8; ++r) {
                uint4 v = rp[q * 8 + r];
                rv[4 * r + 0] = v.x; rv[4 * r + 1] = v.y;
                rv[4 * r + 2] = v.z; rv[4 * r + 3] = v.w;
            }
            float p0 = 0.f, p1 = 0.f;
#pragma unroll
            for (int tq = 0; tq < 8; ++tq) {
                uint4 wv = whhS[(q * 8 + tq) * 256 + jj];
                p0 = dot2acc(wv.x, rv[4 * tq + 0], p0);
                p0 = dot2acc(wv.y, rv[4 * tq + 1], p0);
                p0 = dot2acc(wv.z, rv[4 * tq + 2], p0);
                p0 = dot2acc(wv.w, rv[4 * tq + 3], p0);
            }
#pragma unroll
            for (int tq = 0; tq < 8; ++tq) {
                uint4 wv = whhS[(q * 8 + tq) * 256 + jj + 128];
                p1 = dot2acc(wv.x, rv[4 * tq + 0], p1);
                p1 = dot2acc(wv.y, rv[4 * tq + 1], p1);
                p1 = dot2acc(wv.z, rv[4 * tq + 2], p1);
                p1 = dot2acc(wv.w, rv[4 * tq + 3], p1);
            }
            psum[jj * 5 + q] = p0;
            psum[(128 + jj) * 5 + q] = p1;
        }
        __syncthreads();  // B6: stage-2 partials ready

        float v4b[4] = {0.f, 0.f, 0.f, 0.f};
        float mh = 0.f;
        if (owner) {
            mh = psum[j * 5] + psum[j * 5 + 1] + psum[j * 5 + 2] + psum[j * 5 + 3];
            v4b[0] = mh * mh; v4b[1] = mh * uxh; v4b[2] = mh * bh; v4b[3] = hy * mh;
        }
        bredDB<4>(v4b, redbuf[0], tid);

        float v2[2] = {0.f, 0.f};
        if (owner) {
            float S_mh2 = v4b[0], S_mhu = v4b[1], S_mhb = v4b[2], S_hymh = v4b[3];
            float xnrh = fmaxf(rhn, MINN);
            float axrh = artan_k_(xnrh, sk) / xnrh;
            float mxn = fmaxf(sqrtf(S_mh2), MINN);
            float tk = tan_k_(mxn * axrh, sk);
            float f = tk / mxn;
            float x2 = f * f * S_mh2, y2 = unh * unh, xy = f * S_mhu;
            float a = 1.f - 2.f * k * xy - k * y2;
            float bq = 1.f + k * x2;
            float d = fmaxf(1.f - 2.f * k * xy + k * k * x2 * y2, MINN);
            float c1 = (a * f * mh + bq * uxh) / d;
            float Sc12 = (a * a * x2 + 2.f * a * bq * xy + bq * bq * y2) / (d * d);
            float Sc1b = (a * f * S_mhb + bq * S_ubh) / d;
            float S_hyc1 = (a * f * S_hymh + bq * chy * S_huxh) / d;
            float g = 1.f - 2.f * k * Sc1b - k * bn2h;
            float dl = 1.f + k * Sc12;
            float e = fmaxf(1.f - 2.f * k * Sc1b + k * k * Sc12 * bn2h, MINN);
            float htl = (g * c1 + dl * bh) / e;
            float Shtl2 = (g * g * Sc12 + 2.f * g * dl * Sc1b + dl * dl * bn2h) / (e * e);
            float S_hyhtl = (g * S_hyc1 + dl * chy * S_hbh) / e;
            float ad = 1.f + 2.f * k * S_hyhtl - k * Shtl2;
            float bd = 1.f + k * Shy2;
            float dd = fmaxf(1.f + 2.f * k * S_hyhtl + k * k * Shy2 * Shtl2, MINN);
            float delta = (ad * (-hy) + bd * htl) / dd;
            Sdelta2 = (ad * ad * Shy2 - 2.f * ad * bd * S_hyhtl + bd * bd * Shtl2) / (dd * dd);
            wz = z_t * delta;
            v2[0] = wz * wz; v2[1] = hy * wz;
        }
        bredDB<2>(v2, redbuf[1], tid);

        if (owner) {
            float S_wz2 = v2[0], S_hywz = v2[1];
            float dnc = fmaxf(sqrtf(Sdelta2), MINN);
            float axd = artan_k_(dnc, sk) / dnc;
            float wzt = sqrtf(S_wz2);
            float wznc = fmaxf(wzt, MINN);
            float tkzd = tan_k_(wznc * axd, sk);
            float fz = tkzd / wznc;
            float zd = fz * wz;
            float zdn2 = fz * fz * S_wz2;
            float S_hyzd = fz * S_hywz;
            float an = 1.f - 2.f * k * S_hyzd - k * zdn2;
            float bn_ = 1.f + k * Shy2;
            float dnn = fmaxf(1.f - 2.f * k * S_hyzd + k * k * Shy2 * zdn2, MINN);
            float hnew = (an * hy + bn_ * zd) / dnn;
            float Shnew2 = (an * an * Shy2 + 2.f * an * bn_ * S_hyzd + bn_ * bn_ * zdn2) / (dnn * dnn);
            float yn = fmaxf(sqrtf(Shnew2), MINN);
            float ayn = artan_k_(yn, sk) / yn;
            float outv = ayn * hnew;
            myout[(size_t)t * stride_t + j] = outv;
            h = outv;
            S_h2 = ayn * ayn * Shnew2;
        }
    }
    if (owner) hcar[bb * 256 + j] = h;
}

// ---------- host launcher ----------
extern "C" void kernel_launch(void* const* d_in, const int* in_sizes, int n_in,
                              void* d_out, int out_size, void* d_ws, size_t ws_size,
                              hipStream_t stream) {
    const float* x    = (const float*)d_in[0];
    const float* kptr = (const float*)d_in[1];
    const float* h0   = (const float*)d_in[2];
    const float* wih0 = (const float*)d_in[3];
    const float* whh0 = (const float*)d_in[4];
    const float* b0   = (const float*)d_in[5];
    const float* wih1 = (const float*)d_in[6];
    const float* whh1 = (const float*)d_in[7];
    const float* b1   = (const float*)d_in[8];
    float* out = (float*)d_out;
    float* ws  = (float*)d_ws;

    const int B = 64, T = 1024, H = 256;
    const int CT = 64, NC = 16;
    const int RC = B * CT;  // 4096

    float* wt_ih0 = ws;
    float* wt_ih1 = wt_ih0 + 196608;
    uint32_t* w1pk0  = (uint32_t*)(wt_ih1 + 196608);
    uint32_t* w1pk1  = w1pk0 + 65536;
    uint32_t* whh2g0 = w1pk1 + 65536;
    uint32_t* whh2g1 = whh2g0 + 32768;
    float* hcar  = (float*)(whh2g1 + 32768);
    float* s0    = hcar + 32768;
    float* ax0   = s0 + RC;
    float* s1    = ax0 + RC;
    float* ax1   = s1 + RC;
    float* uxn0  = ax1 + RC;
    float* uxn1  = uxn0 + 3 * RC;
    float* out0c = uxn1 + 3 * RC;
    float* mx0   = out0c + (size_t)RC * H;
    float* mx1   = mx0 + (size_t)RC * 768;

    float* hcar0 = hcar;
    float* hcar1 = hcar + (size_t)B * H;

    dim3 blk(256);
    kt_transpose<<<dim3(1536), blk, 0, stream>>>(wih0, wih1, wt_ih0, wt_ih1);
    kt_prep1<<<dim3(512), blk, 0, stream>>>(whh0, whh1, w1pk0, w1pk1);
    kt_prep2<<<dim3(256), blk, 0, stream>>>(whh0, whh1, whh2g0, whh2g1);
    kt_init<<<dim3(128), blk, 0, stream>>>(h0, hcar);

    const long long sbx = (long long)T * 256;
    const long long sbc = (long long)CT * 256;

    // ---- prologue: layer 0, chunk 0 ----
    {
        const float* xc = x;
        kt_rowscale<<<dim3(RC / 4), blk, 0, stream>>>(xc, sbx, s0, ax0, kptr, 0);
        kt_gemm<<<dim3(12, RC / 64), blk, 0, stream>>>(xc, sbx, s0, wt_ih0, mx0);
        kt_mscale<<<dim3(RC * 3 / 4), blk, 0, stream>>>(mx0, ax0, uxn0, kptr);
        kt_scan2<<<dim3(B), dim3(512), 0, stream>>>(
            mx0, uxn0, w1pk0, whh2g0, b0, hcar0, out0c, sbc, 256LL,
            mx0, uxn0, w1pk0, whh2g0, b0, hcar0, out0c, sbc, 256LL,
            kptr, CT, B);
    }
    // ---- steady state: dual scans (L0 chunk c || L1 chunk c-1) ----
    for (int c = 1; c < NC; ++c) {
        const float* xc = x + (size_t)c * CT * 256;
        kt_rowscale<<<dim3(RC / 4), blk, 0, stream>>>(xc, sbx, s0, ax0, kptr, 0);
        kt_gemm<<<dim3(12, RC / 64), blk, 0, stream>>>(xc, sbx, s0, wt_ih0, mx0);
        kt_mscale<<<dim3(RC * 3 / 4), blk, 0, stream>>>(mx0, ax0, uxn0, kptr);
        kt_rowscale<<<dim3(RC / 4), blk, 0, stream>>>(out0c, sbc, s1, ax1, kptr, 1);
        kt_gemm<<<dim3(12, RC / 64), blk, 0, stream>>>(out0c, sbc, s1, wt_ih1, mx1);
        kt_mscale<<<dim3(RC * 3 / 4), blk, 0, stream>>>(mx1, ax1, uxn1, kptr);
        kt_scan2<<<dim3(2 * B), dim3(512), 0, stream>>>(
            mx0, uxn0, w1pk0, whh2g0, b0, hcar0, out0c, sbc, 256LL,
            mx1, uxn1, w1pk1, whh2g1, b1, hcar1,
            out + (size_t)(c - 1) * CT * B * H, 256LL, (long long)B * H,
            kptr, CT, B);
    }
    // ---- epilogue: layer 1, chunk NC-1 ----
    {
        kt_rowscale<<<dim3(RC / 4), blk, 0, stream>>>(out0c, sbc, s1, ax1, kptr, 1);
        kt_gemm<<<dim3(12, RC / 64), blk, 0, stream>>>(out0c, sbc, s1, wt_ih1, mx1);
        kt_mscale<<<dim3(RC * 3 / 4), blk, 0, stream>>>(mx1, ax1, uxn1, kptr);
        kt_scan2<<<dim3(B), dim3(512), 0, stream>>>(
            mx1, uxn1, w1pk1, whh2g1, b1, hcar1,
            out + (size_t)(NC - 1) * CT * B * H, 256LL, (long long)B * H,
            mx1, uxn1, w1pk1, whh2g1, b1, hcar1,
            out + (size_t)(NC - 1) * CT * B * H, 256LL, (long long)B * H,
            kptr, CT, B);
    }
    kt_final<<<dim3(128), blk, 0, stream>>>(hcar, out + (size_t)T * B * H);
}